// Round 1
// baseline (2032.688 us; speedup 1.0000x reference)
//
#include <hip/hip_runtime.h>

// 2-layer LSTM (H=128) + FC, round 12: FULL LAYER FUSION.
//
// r11 counters: MfmaUtil 26 / VALUBusy 38 / HBM 2% -> stall-bound on ~1024
// serial barrier-steps (A then C) plus phase B's h1g HBM round-trip.
// v12: one fused loop, iteration s = layer0 step s + layer1 step s-1.
// Layer1's two GEMMs fold into one K=256 concat [w_ih1 | w_hh1] acting on
// [h1[s-1]; h2[s-2]]; the h1 A-frags are shared with layer0's recurrence
// GEMM (8 ds_read_b128/step total). Phase B, h1g (128 MB round-trip),
// stage buffer and vmcnt drains are all deleted. 513 barriers total.
// Stationary weights: bf0 16 frags (64 VGPR) + bf1 32 frags (128 VGPR);
// A-frags sequenced through one array to stay near the 256-reg cap.

#define SEQ    512
#define HID    128
#define NTHR   512
#define NBLK   256

typedef _Float16 half_t;
typedef __attribute__((ext_vector_type(2))) _Float16 half2_t;
typedef __attribute__((ext_vector_type(8))) _Float16 half8_t;
typedef __attribute__((ext_vector_type(4))) float floatx4;

__device__ __forceinline__ half2_t pkrtz(float a, float b) {
    return __builtin_bit_cast(half2_t, __builtin_amdgcn_cvt_pkrtz(a, b));
}
__device__ __forceinline__ float dot2f(half2_t a, half2_t b, float c) {
    return __builtin_amdgcn_fdot2(a, b, c, false);
}
__device__ __forceinline__ float sigm(float v) { return 1.0f / (1.0f + __expf(-v)); }
__device__ __forceinline__ float tanh_fast(float v) {
    float e = __expf(2.0f * v);
    return 1.0f - 2.0f / (e + 1.0f);
}
__device__ __forceinline__ float selr(floatx4 v, int r) {
    float a = (r & 1) ? v[1] : v[0];
    float b = (r & 1) ? v[3] : v[2];
    return (r & 2) ? b : a;
}

__global__ void __launch_bounds__(NTHR)
lstm2_v12(const float* __restrict__ x,
          const float* __restrict__ w_ih0, const float* __restrict__ w_hh0,
          const float* __restrict__ b_ih0, const float* __restrict__ b_hh0,
          const float* __restrict__ w_ih1, const float* __restrict__ w_hh1,
          const float* __restrict__ b_ih1, const float* __restrict__ b_hh1,
          const float* __restrict__ fc_w,  const float* __restrict__ fc_b,
          float* __restrict__ out)
{
    const int t   = threadIdx.x;
    const int w   = t >> 6;
    const int l   = t & 63;
    const int m16 = l & 15;
    const int kg  = l >> 4;            // frag k-group; pointwise batch row
    const int jj  = (w << 4) | m16;    // hidden index 0..127
    const int row0 = blockIdx.x * 4;

    __shared__ __align__(16) half2_t xs2[SEQ][4][4];   // 32 KB (16B/(s,row), [3] pad)
    __shared__ __align__(16) half_t h1t[2][4][64][8];  // 8 KB frag-order tiles
    __shared__ __align__(16) half_t h2t[2][4][64][8];  // 8 KB
    __shared__ float wpart[8][4];

    // ---- stationary weight fragments ----
    half8_t bf0[4][4];                 // w_hh0:            64 VGPR
    half8_t bf1[8][4];                 // [w_ih1 | w_hh1]: 128 VGPR
#pragma unroll
    for (int kt = 0; kt < 4; ++kt)
#pragma unroll
        for (int nt = 0; nt < 4; ++nt) {
            const float* p = w_hh0 + (size_t)(nt * HID + jj) * HID + kt * 32 + kg * 8;
            float4 a = *(const float4*)p;
            float4 b = *(const float4*)(p + 4);
            half8_t v;
            v[0]=(half_t)a.x; v[1]=(half_t)a.y; v[2]=(half_t)a.z; v[3]=(half_t)a.w;
            v[4]=(half_t)b.x; v[5]=(half_t)b.y; v[6]=(half_t)b.z; v[7]=(half_t)b.w;
            bf0[kt][nt] = v;
        }
#pragma unroll
    for (int kt = 0; kt < 8; ++kt) {
        const float* W = (kt < 4) ? w_ih1 : w_hh1;
        const int kc = (kt & 3) * 32;
#pragma unroll
        for (int nt = 0; nt < 4; ++nt) {
            const float* p = W + (size_t)(nt * HID + jj) * HID + kc + kg * 8;
            float4 a = *(const float4*)p;
            float4 b = *(const float4*)(p + 4);
            half8_t v;
            v[0]=(half_t)a.x; v[1]=(half_t)a.y; v[2]=(half_t)a.z; v[3]=(half_t)a.w;
            v[4]=(half_t)b.x; v[5]=(half_t)b.y; v[6]=(half_t)b.z; v[7]=(half_t)b.w;
            bf1[kt][nt] = v;
        }
    }

    float bias0v[4], bias1v[4];
#pragma unroll
    for (int nt = 0; nt < 4; ++nt) {
        int g = nt * HID + jj;
        bias0v[nt] = b_ih0[g] + b_hh0[g];
        bias1v[nt] = b_ih1[g] + b_hh1[g];
    }
    half2_t wxh[4][3];                 // layer-0 x weights, packed fp16
#pragma unroll
    for (int nt = 0; nt < 4; ++nt) {
        const float* p = w_ih0 + (nt * HID + jj) * 5;
        wxh[nt][0] = pkrtz(p[0], p[1]);
        wxh[nt][1] = pkrtz(p[2], p[3]);
        wxh[nt][2] = pkrtz(p[4], 0.0f);
    }

    // ---- one-time preloads ----
    for (int i = t; i < SEQ * 4; i += NTHR) {          // x -> packed half2 LDS
        int s = i >> 2, r = i & 3;
        const float* p = x + (size_t)(row0 + r) * (SEQ * 5) + s * 5;
        half2_t* d = &xs2[s][r][0];
        d[0] = pkrtz(p[0], p[1]);
        d[1] = pkrtz(p[2], p[3]);
        d[2] = pkrtz(p[4], 0.0f);
    }
    for (int i = t; i < 4096; i += NTHR) {
        ((half_t*)h1t)[i] = (half_t)0;
        ((half_t*)h2t)[i] = (half_t)0;
    }
    // tile-write coordinates for element (row kg, hidden jj):
    const int kts  = jj >> 5;
    const int slot = (jj >> 3) & 3;
    const int je   = jj & 7;
    float c1 = 0.0f, c2 = 0.0f, h2v = 0.0f;
    __syncthreads();

    // ================= FUSED LOOP: l0 step s + l1 step s-1 =================
#pragma unroll 1
    for (int s = 0; s <= SEQ; ++s) {
        const int pb = s & 1, nb = pb ^ 1;

        half8_t fA[4];                                   // h1[s-1] frags
#pragma unroll
        for (int kt = 0; kt < 4; ++kt)
            fA[kt] = *(const half8_t*)&h1t[pb][kt][l][0];

        floatx4 acc0[4], acc1[4];
#pragma unroll
        for (int nt = 0; nt < 4; ++nt) {
            acc0[nt] = (floatx4){bias0v[nt], bias0v[nt], bias0v[nt], bias0v[nt]};
            acc1[nt] = (floatx4){bias1v[nt], bias1v[nt], bias1v[nt], bias1v[nt]};
        }
        // layer-0 recurrence GEMM (K=128) — shares fA with layer-1 input GEMM
#pragma unroll
        for (int kt = 0; kt < 4; ++kt)
#pragma unroll
            for (int nt = 0; nt < 4; ++nt)
                acc0[nt] = __builtin_amdgcn_mfma_f32_16x16x32_f16(fA[kt], bf0[kt][nt], acc0[nt], 0, 0, 0);
        // layer-1 input half (kt 0..3 of K=256 concat): w_ih1 . h1[s-1]
#pragma unroll
        for (int kt = 0; kt < 4; ++kt)
#pragma unroll
            for (int nt = 0; nt < 4; ++nt)
                acc1[nt] = __builtin_amdgcn_mfma_f32_16x16x32_f16(fA[kt], bf1[kt][nt], acc1[nt], 0, 0, 0);

        // layer-0 pointwise (acc0 dies here, before fA is reloaded)
        if (s < SEQ) {
            const half2_t* xr = &xs2[s][kg][0];
            half2_t x01 = xr[0], x23 = xr[1], x4z = xr[2];
            float gi = selr(acc0[0], kg) + dot2f(x4z, wxh[0][2], dot2f(x23, wxh[0][1], dot2f(x01, wxh[0][0], 0.f)));
            float gf = selr(acc0[1], kg) + dot2f(x4z, wxh[1][2], dot2f(x23, wxh[1][1], dot2f(x01, wxh[1][0], 0.f)));
            float gg = selr(acc0[2], kg) + dot2f(x4z, wxh[2][2], dot2f(x23, wxh[2][1], dot2f(x01, wxh[2][0], 0.f)));
            float go = selr(acc0[3], kg) + dot2f(x4z, wxh[3][2], dot2f(x23, wxh[3][1], dot2f(x01, wxh[3][0], 0.f)));
            float iv = sigm(gi), fv = sigm(gf), gv = tanh_fast(gg), ov = sigm(go);
            c1 = fmaf(fv, c1, iv * gv);
            half_t hh = (half_t)(ov * tanh_fast(c1));
#pragma unroll
            for (int a2 = 0; a2 < 4; ++a2)
                h1t[nb][kts][slot * 16 + kg + 4 * a2][je] = hh;   // M-replication
        }

        // layer-1 recurrent half (kt 4..7): w_hh1 . h2[s-2]; fA reused
#pragma unroll
        for (int kt = 0; kt < 4; ++kt)
            fA[kt] = *(const half8_t*)&h2t[pb][kt][l][0];
#pragma unroll
        for (int kt = 0; kt < 4; ++kt)
#pragma unroll
            for (int nt = 0; nt < 4; ++nt)
                acc1[nt] = __builtin_amdgcn_mfma_f32_16x16x32_f16(fA[kt], bf1[4 + kt][nt], acc1[nt], 0, 0, 0);

        // layer-1 pointwise (step s-1)
        if (s > 0) {
            float gi = selr(acc1[0], kg);
            float gf = selr(acc1[1], kg);
            float gg = selr(acc1[2], kg);
            float go = selr(acc1[3], kg);
            float iv = sigm(gi), fv = sigm(gf), gv = tanh_fast(gg), ov = sigm(go);
            c2 = fmaf(fv, c2, iv * gv);
            h2v = ov * tanh_fast(c2);
            half_t hh = (half_t)h2v;
#pragma unroll
            for (int a2 = 0; a2 < 4; ++a2)
                h2t[nb][kts][slot * 16 + kg + 4 * a2][je] = hh;
        }
        __syncthreads();
    }

    // ---- epilogue: out[row] = fc_b + sum_j fc_w[j] * h2[511][row][j] ----
    float p = fc_w[jj] * h2v;                        // lane = (row kg, col jj)
    p += __shfl_xor(p, 1);
    p += __shfl_xor(p, 2);
    p += __shfl_xor(p, 4);
    p += __shfl_xor(p, 8);
    if (m16 == 0) wpart[w][kg] = p;
    __syncthreads();
    if (t < 4) {
        float ssum = fc_b[0];
#pragma unroll
        for (int wv = 0; wv < 8; ++wv) ssum += wpart[wv][t];
        out[row0 + t] = ssum;
    }
}

extern "C" void kernel_launch(void* const* d_in, const int* in_sizes, int n_in,
                              void* d_out, int out_size, void* d_ws, size_t ws_size,
                              hipStream_t stream) {
    (void)in_sizes; (void)n_in; (void)ws_size; (void)out_size; (void)d_ws;
    const float* x     = (const float*)d_in[0];
    const float* w_ih0 = (const float*)d_in[1];
    const float* w_hh0 = (const float*)d_in[2];
    const float* b_ih0 = (const float*)d_in[3];
    const float* b_hh0 = (const float*)d_in[4];
    const float* w_ih1 = (const float*)d_in[5];
    const float* w_hh1 = (const float*)d_in[6];
    const float* b_ih1 = (const float*)d_in[7];
    const float* b_hh1 = (const float*)d_in[8];
    const float* fc_w  = (const float*)d_in[9];
    const float* fc_b  = (const float*)d_in[10];
    float* out = (float*)d_out;

    lstm2_v12<<<NBLK, NTHR, 0, stream>>>(x, w_ih0, w_hh0, b_ih0, b_hh0,
                                         w_ih1, w_hh1, b_ih1, b_hh1,
                                         fc_w, fc_b, out);
}

// Round 2
// 1147.368 us; speedup vs baseline: 1.7716x; 1.7716x over previous
//
#include <hip/hip_runtime.h>

// 2-layer LSTM (H=128) + FC, round 13: fused loop + explicit 256-reg plan.
//
// v12 post-mortem: compiler default-capped at 128 VGPRs and spilled the
// entire 192-reg stationary weight set to scratch (WRITE_SIZE 126 MB =
// one-time spill stores; per-step scratch reloads -> 9300 cy/step).
// v13 keeps the fused structure (513 barriers, no h1g round-trip) and
// makes the allocation fit 256 regs (2 waves/SIMD; 256 blk on 256 CUs so
// occupancy beyond 1 block/CU is unreachable anyway):
//   - __launch_bounds__(512, 2): grant the full 256-reg budget.
//   - wxh (layer-0 x weights, 12 regs) -> LDS, re-read per step via an
//     opaque zero offset (asm volatile) so LICM can't re-hoist to regs.
//   - ONE acc[4] reused by both layers: l0 GEMM -> l0 pointwise (acc
//     dies) -> l1 K=256 GEMM -> l1 pointwise. sched_barrier(DS_READ)
//     keeps l1 MFMAs from hoisting above the l0 pointwise (would make
//     two acc generations co-live).
//   - A-frags stream through a 2-slot rotation (8 regs, not 16); h1
//     frags are re-read for the l1 input half (4 extra b128/step).
// Stationary: bf0 64 + bf1 128 + bias 8 + misc ~12 = ~212 persistent,
// ~240 peak.

#define SEQ    512
#define HID    128
#define NTHR   512
#define NBLK   256

typedef _Float16 half_t;
typedef __attribute__((ext_vector_type(2))) _Float16 half2_t;
typedef __attribute__((ext_vector_type(8))) _Float16 half8_t;
typedef __attribute__((ext_vector_type(4))) float floatx4;

__device__ __forceinline__ half2_t pkrtz(float a, float b) {
    return __builtin_bit_cast(half2_t, __builtin_amdgcn_cvt_pkrtz(a, b));
}
__device__ __forceinline__ half2_t bch2(float f) {
    return __builtin_bit_cast(half2_t, f);
}
__device__ __forceinline__ float dot2f(half2_t a, half2_t b, float c) {
    return __builtin_amdgcn_fdot2(a, b, c, false);
}
__device__ __forceinline__ float sigm(float v) { return 1.0f / (1.0f + __expf(-v)); }
__device__ __forceinline__ float tanh_fast(float v) {
    float e = __expf(2.0f * v);
    return 1.0f - 2.0f / (e + 1.0f);
}
__device__ __forceinline__ float selr(floatx4 v, int r) {
    float a = (r & 1) ? v[1] : v[0];
    float b = (r & 1) ? v[3] : v[2];
    return (r & 2) ? b : a;
}

__global__ void __launch_bounds__(NTHR, 2)
lstm2_v13(const float* __restrict__ x,
          const float* __restrict__ w_ih0, const float* __restrict__ w_hh0,
          const float* __restrict__ b_ih0, const float* __restrict__ b_hh0,
          const float* __restrict__ w_ih1, const float* __restrict__ w_hh1,
          const float* __restrict__ b_ih1, const float* __restrict__ b_hh1,
          const float* __restrict__ fc_w,  const float* __restrict__ fc_b,
          float* __restrict__ out)
{
    const int t   = threadIdx.x;
    const int w   = t >> 6;
    const int l   = t & 63;
    const int m16 = l & 15;
    const int kg  = l >> 4;            // frag k-group; pointwise batch row
    const int jj  = (w << 4) | m16;    // hidden index 0..127
    const int row0 = blockIdx.x * 4;

    __shared__ __align__(16) half2_t xs2[SEQ][4][4];    // 32 KB
    __shared__ __align__(16) half_t  h1t[2][4][64][8];  // 8 KB frag-order
    __shared__ __align__(16) half_t  h2t[2][4][64][8];  // 8 KB
    __shared__ __align__(16) half2_t wxh_lds[HID][12];  // 6 KB l0 x-weights
    __shared__ float wpart[8][4];

    // ---- stationary weight fragments (192 VGPRs) ----
    half8_t bf0[4][4];                 // w_hh0
    half8_t bf1[8][4];                 // [w_ih1 | w_hh1] K=256 concat
#pragma unroll
    for (int kt = 0; kt < 4; ++kt)
#pragma unroll
        for (int nt = 0; nt < 4; ++nt) {
            const float* p = w_hh0 + (size_t)(nt * HID + jj) * HID + kt * 32 + kg * 8;
            float4 a = *(const float4*)p;
            float4 b = *(const float4*)(p + 4);
            half8_t v;
            v[0]=(half_t)a.x; v[1]=(half_t)a.y; v[2]=(half_t)a.z; v[3]=(half_t)a.w;
            v[4]=(half_t)b.x; v[5]=(half_t)b.y; v[6]=(half_t)b.z; v[7]=(half_t)b.w;
            bf0[kt][nt] = v;
        }
#pragma unroll
    for (int kt = 0; kt < 8; ++kt) {
        const float* W = (kt < 4) ? w_ih1 : w_hh1;
        const int kc = (kt & 3) * 32;
#pragma unroll
        for (int nt = 0; nt < 4; ++nt) {
            const float* p = W + (size_t)(nt * HID + jj) * HID + kc + kg * 8;
            float4 a = *(const float4*)p;
            float4 b = *(const float4*)(p + 4);
            half8_t v;
            v[0]=(half_t)a.x; v[1]=(half_t)a.y; v[2]=(half_t)a.z; v[3]=(half_t)a.w;
            v[4]=(half_t)b.x; v[5]=(half_t)b.y; v[6]=(half_t)b.z; v[7]=(half_t)b.w;
            bf1[kt][nt] = v;
        }
    }

    float bias0v[4], bias1v[4];
#pragma unroll
    for (int nt = 0; nt < 4; ++nt) {
        int g = nt * HID + jj;
        bias0v[nt] = b_ih0[g] + b_hh0[g];
        bias1v[nt] = b_ih1[g] + b_hh1[g];
    }

    // ---- one-time preloads ----
    for (int i = t; i < SEQ * 4; i += NTHR) {          // x -> packed half2 LDS
        int s = i >> 2, r = i & 3;
        const float* p = x + (size_t)(row0 + r) * (SEQ * 5) + s * 5;
        half2_t* d = &xs2[s][r][0];
        d[0] = pkrtz(p[0], p[1]);
        d[1] = pkrtz(p[2], p[3]);
        d[2] = pkrtz(p[4], 0.0f);
    }
    if (t < HID) {                                     // l0 x-weights -> LDS
#pragma unroll
        for (int nt = 0; nt < 4; ++nt) {
            const float* p = w_ih0 + (nt * HID + t) * 5;
            wxh_lds[t][nt * 3 + 0] = pkrtz(p[0], p[1]);
            wxh_lds[t][nt * 3 + 1] = pkrtz(p[2], p[3]);
            wxh_lds[t][nt * 3 + 2] = pkrtz(p[4], 0.0f);
        }
    }
    for (int i = t; i < 4096; i += NTHR) {
        ((half_t*)h1t)[i] = (half_t)0;
        ((half_t*)h2t)[i] = (half_t)0;
    }
    const int kts  = jj >> 5;
    const int slot = (jj >> 3) & 3;
    const int je   = jj & 7;
    float c1 = 0.0f, c2 = 0.0f, h2v = 0.0f;
    __syncthreads();

    // ================= FUSED LOOP: l0 step s + l1 step s-1 =================
#pragma unroll 1
    for (int s = 0; s <= SEQ; ++s) {
        const int pb = s & 1, nb = pb ^ 1;
        const half_t* h1r = &h1t[pb][0][l][0];   // kt stride = 512 halves
        const half_t* h2r = &h2t[pb][0][l][0];

        floatx4 acc[4];
        // ---- layer-0 recurrence GEMM (K=128), 2-slot A-frag rotation ----
        half8_t f0 = *(const half8_t*)(h1r);
        half8_t f1 = *(const half8_t*)(h1r + 512);
#pragma unroll
        for (int nt = 0; nt < 4; ++nt)
            acc[nt] = (floatx4){bias0v[nt], bias0v[nt], bias0v[nt], bias0v[nt]};
#pragma unroll
        for (int nt = 0; nt < 4; ++nt)
            acc[nt] = __builtin_amdgcn_mfma_f32_16x16x32_f16(f0, bf0[0][nt], acc[nt], 0, 0, 0);
        f0 = *(const half8_t*)(h1r + 1024);
#pragma unroll
        for (int nt = 0; nt < 4; ++nt)
            acc[nt] = __builtin_amdgcn_mfma_f32_16x16x32_f16(f1, bf0[1][nt], acc[nt], 0, 0, 0);
        f1 = *(const half8_t*)(h1r + 1536);
#pragma unroll
        for (int nt = 0; nt < 4; ++nt)
            acc[nt] = __builtin_amdgcn_mfma_f32_16x16x32_f16(f0, bf0[2][nt], acc[nt], 0, 0, 0);
#pragma unroll
        for (int nt = 0; nt < 4; ++nt)
            acc[nt] = __builtin_amdgcn_mfma_f32_16x16x32_f16(f1, bf0[3][nt], acc[nt], 0, 0, 0);

        // ---- layer-0 pointwise: acc dies here ----
        if (s < SEQ) {
            int zoff;                               // opaque 0: keep wx in LDS
            asm volatile("v_mov_b32 %0, 0" : "=v"(zoff));
            const char* wxb = (const char*)&wxh_lds[jj][0] + zoff;
            float4 wv0 = *(const float4*)(wxb);
            float4 wv1 = *(const float4*)(wxb + 16);
            float4 wv2 = *(const float4*)(wxb + 32);
            float4 xv  = *(const float4*)&xs2[s][kg][0];
            half2_t x01 = bch2(xv.x), x23 = bch2(xv.y), x4z = bch2(xv.z);
            float gi = selr(acc[0], kg) + dot2f(x4z, bch2(wv0.z), dot2f(x23, bch2(wv0.y), dot2f(x01, bch2(wv0.x), 0.f)));
            float gf = selr(acc[1], kg) + dot2f(x4z, bch2(wv1.y), dot2f(x23, bch2(wv1.x), dot2f(x01, bch2(wv0.w), 0.f)));
            float gg = selr(acc[2], kg) + dot2f(x4z, bch2(wv2.x), dot2f(x23, bch2(wv1.w), dot2f(x01, bch2(wv1.z), 0.f)));
            float go = selr(acc[3], kg) + dot2f(x4z, bch2(wv2.w), dot2f(x23, bch2(wv2.z), dot2f(x01, bch2(wv2.y), 0.f)));
            float iv = sigm(gi), fv = sigm(gf), gv = tanh_fast(gg), ov = sigm(go);
            c1 = fmaf(fv, c1, iv * gv);
            half_t hh = (half_t)(ov * tanh_fast(c1));
#pragma unroll
            for (int a2 = 0; a2 < 4; ++a2)
                h1t[nb][kts][slot * 16 + kg + 4 * a2][je] = hh;   // M-replication
        }
        // pin: l1 MFMAs stay below the l0 pointwise (single live acc gen);
        // DS reads may still hoist for latency hiding.
        __builtin_amdgcn_sched_barrier(0x100);

        // ---- layer-1 GEMM (K=256 concat), reuses acc ----
#pragma unroll
        for (int nt = 0; nt < 4; ++nt)
            acc[nt] = (floatx4){bias1v[nt], bias1v[nt], bias1v[nt], bias1v[nt]};
        f0 = *(const half8_t*)(h1r);
        f1 = *(const half8_t*)(h1r + 512);
#pragma unroll
        for (int nt = 0; nt < 4; ++nt)
            acc[nt] = __builtin_amdgcn_mfma_f32_16x16x32_f16(f0, bf1[0][nt], acc[nt], 0, 0, 0);
        f0 = *(const half8_t*)(h1r + 1024);
#pragma unroll
        for (int nt = 0; nt < 4; ++nt)
            acc[nt] = __builtin_amdgcn_mfma_f32_16x16x32_f16(f1, bf1[1][nt], acc[nt], 0, 0, 0);
        f1 = *(const half8_t*)(h1r + 1536);
#pragma unroll
        for (int nt = 0; nt < 4; ++nt)
            acc[nt] = __builtin_amdgcn_mfma_f32_16x16x32_f16(f0, bf1[2][nt], acc[nt], 0, 0, 0);
        f0 = *(const half8_t*)(h2r);
#pragma unroll
        for (int nt = 0; nt < 4; ++nt)
            acc[nt] = __builtin_amdgcn_mfma_f32_16x16x32_f16(f1, bf1[3][nt], acc[nt], 0, 0, 0);
        f1 = *(const half8_t*)(h2r + 512);
#pragma unroll
        for (int nt = 0; nt < 4; ++nt)
            acc[nt] = __builtin_amdgcn_mfma_f32_16x16x32_f16(f0, bf1[4][nt], acc[nt], 0, 0, 0);
        f0 = *(const half8_t*)(h2r + 1024);
#pragma unroll
        for (int nt = 0; nt < 4; ++nt)
            acc[nt] = __builtin_amdgcn_mfma_f32_16x16x32_f16(f1, bf1[5][nt], acc[nt], 0, 0, 0);
        f1 = *(const half8_t*)(h2r + 1536);
#pragma unroll
        for (int nt = 0; nt < 4; ++nt)
            acc[nt] = __builtin_amdgcn_mfma_f32_16x16x32_f16(f0, bf1[6][nt], acc[nt], 0, 0, 0);
#pragma unroll
        for (int nt = 0; nt < 4; ++nt)
            acc[nt] = __builtin_amdgcn_mfma_f32_16x16x32_f16(f1, bf1[7][nt], acc[nt], 0, 0, 0);

        // ---- layer-1 pointwise (step s-1) ----
        if (s > 0) {
            float gi = selr(acc[0], kg);
            float gf = selr(acc[1], kg);
            float gg = selr(acc[2], kg);
            float go = selr(acc[3], kg);
            float iv = sigm(gi), fv = sigm(gf), gv = tanh_fast(gg), ov = sigm(go);
            c2 = fmaf(fv, c2, iv * gv);
            h2v = ov * tanh_fast(c2);
            half_t hh = (half_t)h2v;
#pragma unroll
            for (int a2 = 0; a2 < 4; ++a2)
                h2t[nb][kts][slot * 16 + kg + 4 * a2][je] = hh;
        }
        __syncthreads();
    }

    // ---- epilogue: out[row] = fc_b + sum_j fc_w[j] * h2[511][row][j] ----
    float p = fc_w[jj] * h2v;                        // lane = (row kg, col jj)
    p += __shfl_xor(p, 1);
    p += __shfl_xor(p, 2);
    p += __shfl_xor(p, 4);
    p += __shfl_xor(p, 8);
    if (m16 == 0) wpart[w][kg] = p;
    __syncthreads();
    if (t < 4) {
        float ssum = fc_b[0];
#pragma unroll
        for (int wv = 0; wv < 8; ++wv) ssum += wpart[wv][t];
        out[row0 + t] = ssum;
    }
}

extern "C" void kernel_launch(void* const* d_in, const int* in_sizes, int n_in,
                              void* d_out, int out_size, void* d_ws, size_t ws_size,
                              hipStream_t stream) {
    (void)in_sizes; (void)n_in; (void)ws_size; (void)out_size; (void)d_ws;
    const float* x     = (const float*)d_in[0];
    const float* w_ih0 = (const float*)d_in[1];
    const float* w_hh0 = (const float*)d_in[2];
    const float* b_ih0 = (const float*)d_in[3];
    const float* b_hh0 = (const float*)d_in[4];
    const float* w_ih1 = (const float*)d_in[5];
    const float* w_hh1 = (const float*)d_in[6];
    const float* b_ih1 = (const float*)d_in[7];
    const float* b_hh1 = (const float*)d_in[8];
    const float* fc_w  = (const float*)d_in[9];
    const float* fc_b  = (const float*)d_in[10];
    float* out = (float*)d_out;

    lstm2_v13<<<NBLK, NTHR, 0, stream>>>(x, w_ih0, w_hh0, b_ih0, b_hh0,
                                         w_ih1, w_hh1, b_ih1, b_hh1,
                                         fc_w, fc_b, out);
}

// Round 3
// 931.953 us; speedup vs baseline: 2.1811x; 1.2311x over previous
//
#include <hip/hip_runtime.h>

// 2-layer LSTM (H=128) + FC, round 14: weights into the idle AGPR file.
//
// v13 post-mortem: launch_bounds(512,2) granted 256 unified regs, but the
// gfx950 MFMA split gave 128 VGPR + 128 AGPR. The 192-reg weight set still
// overflowed the VGPR half (WRITE_SIZE 97 MB = per-step scratch reloads)
// while all 128 AGPRs sat idle.
// v14: bf1 (layer-1 [w_ih1|w_hh1], 128 regs) lives in AGPRs, consumed
// directly by inline-asm v_mfma with "a" operand constraints (ISA: A/B
// may be AGPR). bf0 (64 regs) stays VGPR via the intrinsic. To fit the
// VGPR half: biases -> LDS (added at gate extraction, acc zero-born),
// l0 x-weights stay in LDS behind an opaque per-iteration offset so LICM
// can't re-hoist them. Target: ~128 VGPR + 128 AGPR, zero spill.

#define SEQ    512
#define HID    128
#define NTHR   512
#define NBLK   256

typedef _Float16 half_t;
typedef __attribute__((ext_vector_type(2))) _Float16 half2_t;
typedef __attribute__((ext_vector_type(8))) _Float16 half8_t;
typedef __attribute__((ext_vector_type(4))) float floatx4;

__device__ __forceinline__ half2_t pkrtz(float a, float b) {
    return __builtin_bit_cast(half2_t, __builtin_amdgcn_cvt_pkrtz(a, b));
}
__device__ __forceinline__ half2_t bch2(float f) {
    return __builtin_bit_cast(half2_t, f);
}
__device__ __forceinline__ float dot2f(half2_t a, half2_t b, float c) {
    return __builtin_amdgcn_fdot2(a, b, c, false);
}
__device__ __forceinline__ float sigm(float v) { return 1.0f / (1.0f + __expf(-v)); }
__device__ __forceinline__ float tanh_fast(float v) {
    float e = __expf(2.0f * v);
    return 1.0f - 2.0f / (e + 1.0f);
}
__device__ __forceinline__ float selr(floatx4 v, int r) {
    float a = (r & 1) ? v[1] : v[0];
    float b = (r & 1) ? v[3] : v[2];
    return (r & 2) ? b : a;
}
// MFMA with B-operand pinned to the AGPR file (frees the VGPR half).
__device__ __forceinline__ void mfma_agpr(floatx4& c, half8_t a, half8_t b) {
    asm("v_mfma_f32_16x16x32_f16 %0, %1, %2, %0" : "+v"(c) : "v"(a), "a"(b));
}

__global__ void __launch_bounds__(NTHR, 2)
lstm2_v14(const float* __restrict__ x,
          const float* __restrict__ w_ih0, const float* __restrict__ w_hh0,
          const float* __restrict__ b_ih0, const float* __restrict__ b_hh0,
          const float* __restrict__ w_ih1, const float* __restrict__ w_hh1,
          const float* __restrict__ b_ih1, const float* __restrict__ b_hh1,
          const float* __restrict__ fc_w,  const float* __restrict__ fc_b,
          float* __restrict__ out)
{
    const int t   = threadIdx.x;
    const int w   = t >> 6;
    const int l   = t & 63;
    const int m16 = l & 15;
    const int kg  = l >> 4;            // frag k-group; pointwise batch row
    const int jj  = (w << 4) | m16;    // hidden index 0..127
    const int row0 = blockIdx.x * 4;

    __shared__ __align__(16) half2_t xs2[SEQ][4][4];    // 32 KB
    __shared__ __align__(16) half_t  h1t[2][4][64][8];  // 8 KB frag-order
    __shared__ __align__(16) half_t  h2t[2][4][64][8];  // 8 KB
    __shared__ __align__(16) half2_t wxh_lds[HID][12];  // 6 KB l0 x-weights
    __shared__ __align__(16) float   blds[2][HID][4];   // 4 KB biases
    __shared__ float wpart[8][4];

    // ---- stationary weight fragments ----
    half8_t bf0[4][4];                 // w_hh0: VGPR (intrinsic MFMA)
    half8_t bf1[8][4];                 // [w_ih1|w_hh1]: AGPR ("a" asm MFMA)
#pragma unroll
    for (int kt = 0; kt < 4; ++kt)
#pragma unroll
        for (int nt = 0; nt < 4; ++nt) {
            const float* p = w_hh0 + (size_t)(nt * HID + jj) * HID + kt * 32 + kg * 8;
            float4 a = *(const float4*)p;
            float4 b = *(const float4*)(p + 4);
            half8_t v;
            v[0]=(half_t)a.x; v[1]=(half_t)a.y; v[2]=(half_t)a.z; v[3]=(half_t)a.w;
            v[4]=(half_t)b.x; v[5]=(half_t)b.y; v[6]=(half_t)b.z; v[7]=(half_t)b.w;
            bf0[kt][nt] = v;
        }
#pragma unroll
    for (int kt = 0; kt < 8; ++kt) {
        const float* W = (kt < 4) ? w_ih1 : w_hh1;
        const int kc = (kt & 3) * 32;
#pragma unroll
        for (int nt = 0; nt < 4; ++nt) {
            const float* p = W + (size_t)(nt * HID + jj) * HID + kc + kg * 8;
            float4 a = *(const float4*)p;
            float4 b = *(const float4*)(p + 4);
            half8_t v;
            v[0]=(half_t)a.x; v[1]=(half_t)a.y; v[2]=(half_t)a.z; v[3]=(half_t)a.w;
            v[4]=(half_t)b.x; v[5]=(half_t)b.y; v[6]=(half_t)b.z; v[7]=(half_t)b.w;
            bf1[kt][nt] = v;
        }
    }

    // ---- one-time preloads ----
    for (int i = t; i < SEQ * 4; i += NTHR) {          // x -> packed half2 LDS
        int s = i >> 2, r = i & 3;
        const float* p = x + (size_t)(row0 + r) * (SEQ * 5) + s * 5;
        half2_t* d = &xs2[s][r][0];
        d[0] = pkrtz(p[0], p[1]);
        d[1] = pkrtz(p[2], p[3]);
        d[2] = pkrtz(p[4], 0.0f);
    }
    if (t < HID) {                                     // l0 x-weights -> LDS
#pragma unroll
        for (int nt = 0; nt < 4; ++nt) {
            const float* p = w_ih0 + (nt * HID + t) * 5;
            wxh_lds[t][nt * 3 + 0] = pkrtz(p[0], p[1]);
            wxh_lds[t][nt * 3 + 1] = pkrtz(p[2], p[3]);
            wxh_lds[t][nt * 3 + 2] = pkrtz(p[4], 0.0f);
        }
#pragma unroll
        for (int nt = 0; nt < 4; ++nt) {               // biases -> LDS
            blds[0][t][nt] = b_ih0[nt * HID + t] + b_hh0[nt * HID + t];
            blds[1][t][nt] = b_ih1[nt * HID + t] + b_hh1[nt * HID + t];
        }
    }
    for (int i = t; i < 4096; i += NTHR) {
        ((half_t*)h1t)[i] = (half_t)0;
        ((half_t*)h2t)[i] = (half_t)0;
    }
    const int kts  = jj >> 5;
    const int slot = (jj >> 3) & 3;
    const int je   = jj & 7;
    float c1 = 0.0f, c2 = 0.0f, h2v = 0.0f;
    __syncthreads();

    // ================= FUSED LOOP: l0 step s + l1 step s-1 =================
#pragma unroll 1
    for (int s = 0; s <= SEQ; ++s) {
        const int pb = s & 1, nb = pb ^ 1;
        const half_t* h1r = &h1t[pb][0][l][0];   // kt stride = 512 halves
        const half_t* h2r = &h2t[pb][0][l][0];

        floatx4 acc[4];
        const floatx4 zf = (floatx4){0.f, 0.f, 0.f, 0.f};
        // ---- layer-0 recurrence GEMM (K=128), 2-slot A-frag rotation ----
        half8_t f0 = *(const half8_t*)(h1r);
        half8_t f1 = *(const half8_t*)(h1r + 512);
#pragma unroll
        for (int nt = 0; nt < 4; ++nt)
            acc[nt] = __builtin_amdgcn_mfma_f32_16x16x32_f16(f0, bf0[0][nt], zf, 0, 0, 0);
        f0 = *(const half8_t*)(h1r + 1024);
#pragma unroll
        for (int nt = 0; nt < 4; ++nt)
            acc[nt] = __builtin_amdgcn_mfma_f32_16x16x32_f16(f1, bf0[1][nt], acc[nt], 0, 0, 0);
        f1 = *(const half8_t*)(h1r + 1536);
#pragma unroll
        for (int nt = 0; nt < 4; ++nt)
            acc[nt] = __builtin_amdgcn_mfma_f32_16x16x32_f16(f0, bf0[2][nt], acc[nt], 0, 0, 0);
#pragma unroll
        for (int nt = 0; nt < 4; ++nt)
            acc[nt] = __builtin_amdgcn_mfma_f32_16x16x32_f16(f1, bf0[3][nt], acc[nt], 0, 0, 0);

        // ---- layer-0 pointwise: acc dies here ----
        if (s < SEQ) {
            int zoff;                               // opaque 0: defeat LICM
            asm volatile("v_mov_b32 %0, 0" : "=v"(zoff));
            const char* wxb = (const char*)&wxh_lds[jj][0] + zoff;
            float4 wv0 = *(const float4*)(wxb);
            float4 wv1 = *(const float4*)(wxb + 16);
            float4 wv2 = *(const float4*)(wxb + 32);
            float4 bv0 = *(const float4*)((const char*)&blds[0][jj][0] + zoff);
            float4 xv  = *(const float4*)&xs2[s][kg][0];
            half2_t x01 = bch2(xv.x), x23 = bch2(xv.y), x4z = bch2(xv.z);
            float gi = selr(acc[0], kg) + bv0.x + dot2f(x4z, bch2(wv0.z), dot2f(x23, bch2(wv0.y), dot2f(x01, bch2(wv0.x), 0.f)));
            float gf = selr(acc[1], kg) + bv0.y + dot2f(x4z, bch2(wv1.y), dot2f(x23, bch2(wv1.x), dot2f(x01, bch2(wv0.w), 0.f)));
            float gg = selr(acc[2], kg) + bv0.z + dot2f(x4z, bch2(wv2.x), dot2f(x23, bch2(wv1.w), dot2f(x01, bch2(wv1.z), 0.f)));
            float go = selr(acc[3], kg) + bv0.w + dot2f(x4z, bch2(wv2.w), dot2f(x23, bch2(wv2.z), dot2f(x01, bch2(wv2.y), 0.f)));
            float iv = sigm(gi), fv = sigm(gf), gv = tanh_fast(gg), ov = sigm(go);
            c1 = fmaf(fv, c1, iv * gv);
            half_t hh = (half_t)(ov * tanh_fast(c1));
#pragma unroll
            for (int a2 = 0; a2 < 4; ++a2)
                h1t[nb][kts][slot * 16 + kg + 4 * a2][je] = hh;   // M-replication
        }
        // pin: l1 MFMAs stay below the l0 pointwise (single live acc gen);
        // DS reads may still hoist for latency hiding.
        __builtin_amdgcn_sched_barrier(0x100);

        // ---- layer-1 GEMM (K=256 concat), B from AGPR, reuses acc ----
#pragma unroll
        for (int nt = 0; nt < 4; ++nt)
            acc[nt] = (floatx4){0.f, 0.f, 0.f, 0.f};
        f0 = *(const half8_t*)(h1r);
        f1 = *(const half8_t*)(h1r + 512);
#pragma unroll
        for (int nt = 0; nt < 4; ++nt) mfma_agpr(acc[nt], f0, bf1[0][nt]);
        f0 = *(const half8_t*)(h1r + 1024);
#pragma unroll
        for (int nt = 0; nt < 4; ++nt) mfma_agpr(acc[nt], f1, bf1[1][nt]);
        f1 = *(const half8_t*)(h1r + 1536);
#pragma unroll
        for (int nt = 0; nt < 4; ++nt) mfma_agpr(acc[nt], f0, bf1[2][nt]);
        f0 = *(const half8_t*)(h2r);
#pragma unroll
        for (int nt = 0; nt < 4; ++nt) mfma_agpr(acc[nt], f1, bf1[3][nt]);
        f1 = *(const half8_t*)(h2r + 512);
#pragma unroll
        for (int nt = 0; nt < 4; ++nt) mfma_agpr(acc[nt], f0, bf1[4][nt]);
        f0 = *(const half8_t*)(h2r + 1024);
#pragma unroll
        for (int nt = 0; nt < 4; ++nt) mfma_agpr(acc[nt], f1, bf1[5][nt]);
        f1 = *(const half8_t*)(h2r + 1536);
#pragma unroll
        for (int nt = 0; nt < 4; ++nt) mfma_agpr(acc[nt], f0, bf1[6][nt]);
#pragma unroll
        for (int nt = 0; nt < 4; ++nt) mfma_agpr(acc[nt], f1, bf1[7][nt]);

        // ---- layer-1 pointwise (step s-1) ----
        if (s > 0) {
            int zoff1;
            asm volatile("v_mov_b32 %0, 0" : "=v"(zoff1));
            float4 bv1 = *(const float4*)((const char*)&blds[1][jj][0] + zoff1);
            float gi = selr(acc[0], kg) + bv1.x;
            float gf = selr(acc[1], kg) + bv1.y;
            float gg = selr(acc[2], kg) + bv1.z;
            float go = selr(acc[3], kg) + bv1.w;
            float iv = sigm(gi), fv = sigm(gf), gv = tanh_fast(gg), ov = sigm(go);
            c2 = fmaf(fv, c2, iv * gv);
            h2v = ov * tanh_fast(c2);
            half_t hh = (half_t)h2v;
#pragma unroll
            for (int a2 = 0; a2 < 4; ++a2)
                h2t[nb][kts][slot * 16 + kg + 4 * a2][je] = hh;
        }
        __syncthreads();
    }

    // ---- epilogue: out[row] = fc_b + sum_j fc_w[j] * h2[511][row][j] ----
    float p = fc_w[jj] * h2v;                        // lane = (row kg, col jj)
    p += __shfl_xor(p, 1);
    p += __shfl_xor(p, 2);
    p += __shfl_xor(p, 4);
    p += __shfl_xor(p, 8);
    if (m16 == 0) wpart[w][kg] = p;
    __syncthreads();
    if (t < 4) {
        float ssum = fc_b[0];
#pragma unroll
        for (int wv = 0; wv < 8; ++wv) ssum += wpart[wv][t];
        out[row0 + t] = ssum;
    }
}

extern "C" void kernel_launch(void* const* d_in, const int* in_sizes, int n_in,
                              void* d_out, int out_size, void* d_ws, size_t ws_size,
                              hipStream_t stream) {
    (void)in_sizes; (void)n_in; (void)ws_size; (void)out_size; (void)d_ws;
    const float* x     = (const float*)d_in[0];
    const float* w_ih0 = (const float*)d_in[1];
    const float* w_hh0 = (const float*)d_in[2];
    const float* b_ih0 = (const float*)d_in[3];
    const float* b_hh0 = (const float*)d_in[4];
    const float* w_ih1 = (const float*)d_in[5];
    const float* w_hh1 = (const float*)d_in[6];
    const float* b_ih1 = (const float*)d_in[7];
    const float* b_hh1 = (const float*)d_in[8];
    const float* fc_w  = (const float*)d_in[9];
    const float* fc_b  = (const float*)d_in[10];
    float* out = (float*)d_out;

    lstm2_v14<<<NBLK, NTHR, 0, stream>>>(x, w_ih0, w_hh0, b_ih0, b_hh0,
                                         w_ih1, w_hh1, b_ih1, b_hh1,
                                         fc_w, fc_b, out);
}